// Round 1
// baseline (1841.596 us; speedup 1.0000x reference)
//
#include <hip/hip_runtime.h>
#include <hip/hip_bf16.h>
#include <math.h>

#define N_NODES 100000
#define N_EDGES 3200000
#define F0 489
#define F1 64
#define F2 32
#define F3 2

// ---------------- degree / norm ----------------

__global__ void k_deg_init(float* deg) {
    int i = blockIdx.x * blockDim.x + threadIdx.x;
    if (i < N_NODES) deg[i] = 1.0f;  // self loop
}

__global__ void k_deg_count(const int* __restrict__ dst, float* deg) {
    int e = blockIdx.x * blockDim.x + threadIdx.x;
    if (e < N_EDGES) atomicAdd(&deg[dst[e]], 1.0f);
}

__global__ void k_dinv(const float* __restrict__ deg, float* dinv) {
    int i = blockIdx.x * blockDim.x + threadIdx.x;
    if (i < N_NODES) dinv[i] = rsqrtf(deg[i]);
}

// ---------------- layer 1 GEMM: g1 = dinv .* (x @ W1), agg1 = g1 ----------------
// block = 256 (4 waves), 2 rows per wave -> 8 rows per block. N_NODES % 8 == 0.
__global__ __launch_bounds__(256) void k_gemm1(const float* __restrict__ x,
                                               const float* __restrict__ W1,
                                               const float* __restrict__ dinv,
                                               float* __restrict__ g1,
                                               float* __restrict__ agg1) {
    __shared__ float xs[8][512];  // 16 KB
    int wave = threadIdx.x >> 6;
    int lane = threadIdx.x & 63;
    int r0 = wave * 2;
    int r1 = r0 + 1;
    int row0 = blockIdx.x * 8 + r0;
    int row1 = row0 + 1;

    const float* xr0 = x + (size_t)row0 * F0;
    const float* xr1 = x + (size_t)row1 * F0;
    for (int k = lane; k < F0; k += 64) {
        xs[r0][k] = xr0[k];
        xs[r1][k] = xr1[k];
    }
    // wave-local LDS use: no cross-wave sharing, compiler inserts waitcnt

    float acc0 = 0.f, acc1 = 0.f;
    for (int k = 0; k < 488; k += 4) {
#pragma unroll
        for (int j = 0; j < 4; j++) {
            float w = W1[(k + j) * 64 + lane];
            acc0 += xs[r0][k + j] * w;
            acc1 += xs[r1][k + j] * w;
        }
    }
    {
        float w = W1[488 * 64 + lane];
        acc0 += xs[r0][488] * w;
        acc1 += xs[r1][488] * w;
    }
    float s0 = dinv[row0], s1 = dinv[row1];
    float v0 = s0 * acc0, v1 = s1 * acc1;
    g1[(size_t)row0 * 64 + lane] = v0;
    agg1[(size_t)row0 * 64 + lane] = v0;
    g1[(size_t)row1 * 64 + lane] = v1;
    agg1[(size_t)row1 * 64 + lane] = v1;
}

// ---------------- edge scatter, 64 features ----------------
__global__ __launch_bounds__(256) void k_scatter64(const int* __restrict__ src,
                                                   const int* __restrict__ dst,
                                                   const float* __restrict__ g,
                                                   float* __restrict__ agg) {
    int t = blockIdx.x * 256 + threadIdx.x;
    int e = t >> 6;
    int f = t & 63;
    if (e < N_EDGES) {
        int s = src[e];
        int d = dst[e];
        atomicAdd(&agg[(size_t)d * 64 + f], g[(size_t)s * 64 + f]);
    }
}

// ---------------- layer 2: h1 = relu(dinv*agg1 + b1); g2 = dinv .* (h1 @ W2) ----------------
// block 256, 32 rows per block. N_NODES % 32 == 0.
__global__ __launch_bounds__(256) void k_layer2(const float* __restrict__ agg1,
                                                const float* __restrict__ dinv,
                                                const float* __restrict__ b1,
                                                const float* __restrict__ W2,
                                                float* __restrict__ g2,
                                                float* __restrict__ agg2) {
    __shared__ float hs[32][65];   // +1 pad
    __shared__ float Ws[64 * 32];  // 8 KB
    for (int i = threadIdx.x; i < 64 * 32; i += 256) Ws[i] = W2[i];
    int row0 = blockIdx.x * 32;
    for (int i = threadIdx.x; i < 32 * 64; i += 256) {
        int r = i >> 6, f = i & 63;
        int row = row0 + r;
        float v = dinv[row] * agg1[(size_t)row * 64 + f] + b1[f];
        hs[r][f] = fmaxf(v, 0.f);
    }
    __syncthreads();
    int r = threadIdx.x >> 3;
    int j0 = (threadIdx.x & 7) * 4;
    int row = row0 + r;
    float a0 = 0.f, a1 = 0.f, a2 = 0.f, a3 = 0.f;
#pragma unroll 8
    for (int f = 0; f < 64; f++) {
        float h = hs[r][f];
        a0 += h * Ws[f * 32 + j0 + 0];
        a1 += h * Ws[f * 32 + j0 + 1];
        a2 += h * Ws[f * 32 + j0 + 2];
        a3 += h * Ws[f * 32 + j0 + 3];
    }
    float s = dinv[row];
    float4 v = make_float4(s * a0, s * a1, s * a2, s * a3);
    *reinterpret_cast<float4*>(&g2[(size_t)row * 32 + j0]) = v;
    *reinterpret_cast<float4*>(&agg2[(size_t)row * 32 + j0]) = v;
}

// ---------------- edge scatter, 32 features ----------------
__global__ __launch_bounds__(256) void k_scatter32(const int* __restrict__ src,
                                                   const int* __restrict__ dst,
                                                   const float* __restrict__ g,
                                                   float* __restrict__ agg) {
    int t = blockIdx.x * 256 + threadIdx.x;
    int e = t >> 5;
    int f = t & 31;
    if (e < N_EDGES) {
        int s = src[e];
        int d = dst[e];
        atomicAdd(&agg[(size_t)d * 32 + f], g[(size_t)s * 32 + f]);
    }
}

// ---------------- layer 3: h2 = relu(dinv*agg2 + b2); g3 = dinv .* (h2 @ W3) ----------------
__global__ __launch_bounds__(256) void k_layer3(const float* __restrict__ agg2,
                                                const float* __restrict__ dinv,
                                                const float* __restrict__ b2,
                                                const float* __restrict__ W3,
                                                float* __restrict__ g3,
                                                float* __restrict__ agg3) {
    int row = blockIdx.x * blockDim.x + threadIdx.x;
    if (row >= N_NODES) return;
    float s = dinv[row];
    float t0 = 0.f, t1 = 0.f;
    const float4* ar = reinterpret_cast<const float4*>(agg2 + (size_t)row * 32);
#pragma unroll
    for (int q = 0; q < 8; q++) {
        float4 v = ar[q];
        float h;
        int f = q * 4;
        h = fmaxf(s * v.x + b2[f + 0], 0.f); t0 += h * W3[(f + 0) * 2]; t1 += h * W3[(f + 0) * 2 + 1];
        h = fmaxf(s * v.y + b2[f + 1], 0.f); t0 += h * W3[(f + 1) * 2]; t1 += h * W3[(f + 1) * 2 + 1];
        h = fmaxf(s * v.z + b2[f + 2], 0.f); t0 += h * W3[(f + 2) * 2]; t1 += h * W3[(f + 2) * 2 + 1];
        h = fmaxf(s * v.w + b2[f + 3], 0.f); t0 += h * W3[(f + 3) * 2]; t1 += h * W3[(f + 3) * 2 + 1];
    }
    g3[(size_t)row * 2 + 0] = s * t0;
    g3[(size_t)row * 2 + 1] = s * t1;
    agg3[(size_t)row * 2 + 0] = s * t0;
    agg3[(size_t)row * 2 + 1] = s * t1;
}

// ---------------- edge scatter, 2 features ----------------
__global__ __launch_bounds__(256) void k_scatter2(const int* __restrict__ src,
                                                  const int* __restrict__ dst,
                                                  const float* __restrict__ g,
                                                  float* __restrict__ agg) {
    int t = blockIdx.x * 256 + threadIdx.x;
    int e = t >> 1;
    int f = t & 1;
    if (e < N_EDGES) {
        int s = src[e];
        int d = dst[e];
        atomicAdd(&agg[(size_t)d * 2 + f], g[(size_t)s * 2 + f]);
    }
}

// ---------------- final: out = log_softmax(dinv*agg3 + b3) ----------------
__global__ void k_final(const float* __restrict__ agg3,
                        const float* __restrict__ dinv,
                        const float* __restrict__ b3,
                        float* __restrict__ out) {
    int row = blockIdx.x * blockDim.x + threadIdx.x;
    if (row >= N_NODES) return;
    float s = dinv[row];
    float z0 = s * agg3[(size_t)row * 2 + 0] + b3[0];
    float z1 = s * agg3[(size_t)row * 2 + 1] + b3[1];
    float m = fmaxf(z0, z1);
    float lse = m + logf(expf(z0 - m) + expf(z1 - m));
    out[(size_t)row * 2 + 0] = z0 - lse;
    out[(size_t)row * 2 + 1] = z1 - lse;
}

extern "C" void kernel_launch(void* const* d_in, const int* in_sizes, int n_in,
                              void* d_out, int out_size, void* d_ws, size_t ws_size,
                              hipStream_t stream) {
    const float* x  = (const float*)d_in[0];
    const int*   ei = (const int*)d_in[1];   // [2, E] row-major: src then dst
    const float* W1 = (const float*)d_in[2];
    const float* b1 = (const float*)d_in[3];
    const float* W2 = (const float*)d_in[4];
    const float* b2 = (const float*)d_in[5];
    const float* W3 = (const float*)d_in[6];
    const float* b3 = (const float*)d_in[7];
    float* out = (float*)d_out;

    const int* src = ei;
    const int* dst = ei + N_EDGES;

    float* ws = (float*)d_ws;
    float* deg  = ws;                 // N
    float* dinv = deg  + N_NODES;     // N
    float* g1   = dinv + N_NODES;     // N*64
    float* agg1 = g1   + (size_t)N_NODES * 64;
    float* g2   = agg1 + (size_t)N_NODES * 64;  // N*32
    float* agg2 = g2   + (size_t)N_NODES * 32;
    float* g3   = agg2 + (size_t)N_NODES * 32;  // N*2
    float* agg3 = g3   + (size_t)N_NODES * 2;

    const int TB = 256;
    int nb_nodes = (N_NODES + TB - 1) / TB;  // 391

    k_deg_init<<<nb_nodes, TB, 0, stream>>>(deg);
    k_deg_count<<<(N_EDGES + TB - 1) / TB, TB, 0, stream>>>(dst, deg);
    k_dinv<<<nb_nodes, TB, 0, stream>>>(deg, dinv);

    k_gemm1<<<N_NODES / 8, TB, 0, stream>>>(x, W1, dinv, g1, agg1);
    k_scatter64<<<(size_t)N_EDGES * 64 / TB, TB, 0, stream>>>(src, dst, g1, agg1);

    k_layer2<<<N_NODES / 32, TB, 0, stream>>>(agg1, dinv, b1, W2, g2, agg2);
    k_scatter32<<<(size_t)N_EDGES * 32 / TB, TB, 0, stream>>>(src, dst, g2, agg2);

    k_layer3<<<nb_nodes, TB, 0, stream>>>(agg2, dinv, b2, W3, g3, agg3);
    k_scatter2<<<(size_t)N_EDGES * 2 / TB, TB, 0, stream>>>(src, dst, g3, agg3);

    k_final<<<nb_nodes, TB, 0, stream>>>(agg3, dinv, b3, out);
}

// Round 2
// 1095.057 us; speedup vs baseline: 1.6817x; 1.6817x over previous
//
#include <hip/hip_runtime.h>
#include <hip/hip_bf16.h>
#include <math.h>

#define N_NODES 100000
#define N_EDGES 3200000
#define F0 489
#define NB_SCAN 391   // ceil(100000/256)

// ---------------- zero int buffer ----------------
__global__ void k_zero(int* a, int n) {
    int i = blockIdx.x * blockDim.x + threadIdx.x;
    if (i < n) a[i] = 0;
}

// ---------------- integer degree histogram (dst) ----------------
__global__ void k_count(const int* __restrict__ dst, int* deg) {
    int e = blockIdx.x * blockDim.x + threadIdx.x;
    if (e < N_EDGES) atomicAdd(&deg[dst[e]], 1);
}

// ---------------- dinv = rsqrt(deg+1)  (self loop) ----------------
__global__ void k_dinv(const int* __restrict__ deg, float* dinv) {
    int i = blockIdx.x * blockDim.x + threadIdx.x;
    if (i < N_NODES) dinv[i] = rsqrtf((float)deg[i] + 1.0f);
}

// ---------------- scan: block-wise inclusive (into rowptr), block sums ----------------
__global__ __launch_bounds__(256) void k_scan1(const int* __restrict__ deg,
                                               int* __restrict__ rowptr,
                                               int* __restrict__ bsums) {
    __shared__ int tmp[256];
    int i = blockIdx.x * 256 + threadIdx.x;
    int v = (i < N_NODES) ? deg[i] : 0;
    tmp[threadIdx.x] = v;
    __syncthreads();
    for (int off = 1; off < 256; off <<= 1) {
        int t = (threadIdx.x >= off) ? tmp[threadIdx.x - off] : 0;
        __syncthreads();
        tmp[threadIdx.x] += t;
        __syncthreads();
    }
    if (i < N_NODES) rowptr[i] = tmp[threadIdx.x];   // inclusive, fixed up in scan3
    if (threadIdx.x == 255) bsums[blockIdx.x] = tmp[255];
}

__global__ __launch_bounds__(512) void k_scan2(const int* __restrict__ bsums,
                                               int* __restrict__ boffs) {
    __shared__ int tmp[512];
    int i = threadIdx.x;
    int v = (i < NB_SCAN) ? bsums[i] : 0;
    tmp[i] = v;
    __syncthreads();
    for (int off = 1; off < 512; off <<= 1) {
        int t = (i >= off) ? tmp[i - off] : 0;
        __syncthreads();
        tmp[i] += t;
        __syncthreads();
    }
    if (i < NB_SCAN) boffs[i] = tmp[i] - v;  // exclusive
}

__global__ __launch_bounds__(256) void k_scan3(int* __restrict__ rowptr,
                                               const int* __restrict__ deg,
                                               const int* __restrict__ boffs) {
    int i = blockIdx.x * 256 + threadIdx.x;
    if (i < N_NODES) rowptr[i] = rowptr[i] - deg[i] + boffs[blockIdx.x];  // exclusive
    if (i == 0) rowptr[N_NODES] = N_EDGES;
}

// ---------------- CSR bucket fill ----------------
__global__ void k_fill(const int* __restrict__ src, const int* __restrict__ dst,
                       const int* __restrict__ rowptr, int* __restrict__ cur,
                       int* __restrict__ csr) {
    int e = blockIdx.x * blockDim.x + threadIdx.x;
    if (e < N_EDGES) {
        int d = dst[e];
        int pos = rowptr[d] + atomicAdd(&cur[d], 1);
        csr[pos] = src[e];
    }
}

// ---------------- layer 1 GEMM: g1 = dinv .* (x @ W1) ----------------
__global__ __launch_bounds__(256) void k_gemm1(const float* __restrict__ x,
                                               const float* __restrict__ W1,
                                               const float* __restrict__ dinv,
                                               float* __restrict__ g1) {
    __shared__ float xs[8][512];  // 16 KB
    int wave = threadIdx.x >> 6;
    int lane = threadIdx.x & 63;
    int r0 = wave * 2;
    int r1 = r0 + 1;
    int row0 = blockIdx.x * 8 + r0;
    int row1 = row0 + 1;

    const float* xr0 = x + (size_t)row0 * F0;
    const float* xr1 = x + (size_t)row1 * F0;
    for (int k = lane; k < F0; k += 64) {
        xs[r0][k] = xr0[k];
        xs[r1][k] = xr1[k];
    }

    float acc0 = 0.f, acc1 = 0.f;
    for (int k = 0; k < 488; k += 4) {
#pragma unroll
        for (int j = 0; j < 4; j++) {
            float w = W1[(k + j) * 64 + lane];
            acc0 += xs[r0][k + j] * w;
            acc1 += xs[r1][k + j] * w;
        }
    }
    {
        float w = W1[488 * 64 + lane];
        acc0 += xs[r0][488] * w;
        acc1 += xs[r1][488] * w;
    }
    g1[(size_t)row0 * 64 + lane] = dinv[row0] * acc0;
    g1[(size_t)row1 * 64 + lane] = dinv[row1] * acc1;
}

// ---------------- gather, 64 features: agg[n] = g[n] + sum_{e->n} g[src] ----------------
__global__ __launch_bounds__(256) void k_gather64(const int* __restrict__ rowptr,
                                                  const int* __restrict__ csr,
                                                  const float* __restrict__ g,
                                                  float* __restrict__ agg) {
    int node = blockIdx.x * 4 + (threadIdx.x >> 6);
    int f = threadIdx.x & 63;
    int beg = rowptr[node], end = rowptr[node + 1];
    float acc = g[(size_t)node * 64 + f];  // self loop
    for (int j0 = beg; j0 < end; j0 += 64) {
        int n = end - j0;
        if (n > 64) n = 64;
        int e = csr[j0 + (f < n ? f : 0)];
        for (int i = 0; i < n; i++) {
            int s = __shfl(e, i, 64);
            acc += g[(size_t)s * 64 + f];
        }
    }
    agg[(size_t)node * 64 + f] = acc;
}

// ---------------- gather, 32 features (half-wave per node) ----------------
__global__ __launch_bounds__(256) void k_gather32(const int* __restrict__ rowptr,
                                                  const int* __restrict__ csr,
                                                  const float* __restrict__ g,
                                                  float* __restrict__ agg) {
    int t = blockIdx.x * 256 + threadIdx.x;
    int node = t >> 5;
    int f = t & 31;
    int beg = rowptr[node], end = rowptr[node + 1];
    float acc = g[(size_t)node * 32 + f];
    for (int j0 = beg; j0 < end; j0 += 32) {
        int n = end - j0;
        if (n > 32) n = 32;
        int e = csr[j0 + (f < n ? f : 0)];
        for (int i = 0; i < n; i++) {
            int s = __shfl(e, i, 32);
            acc += g[(size_t)s * 32 + f];
        }
    }
    agg[(size_t)node * 32 + f] = acc;
}

// ---------------- gather, 2 features ----------------
__global__ __launch_bounds__(256) void k_gather2(const int* __restrict__ rowptr,
                                                 const int* __restrict__ csr,
                                                 const float* __restrict__ g,
                                                 float* __restrict__ agg) {
    int t = blockIdx.x * 256 + threadIdx.x;
    if (t >= N_NODES * 2) return;
    int node = t >> 1;
    int f = t & 1;
    int beg = rowptr[node], end = rowptr[node + 1];
    float acc = g[(size_t)node * 2 + f];
    for (int j = beg; j < end; j++) {
        int s = csr[j];
        acc += g[(size_t)s * 2 + f];
    }
    agg[(size_t)node * 2 + f] = acc;
}

// ---------------- layer 2: h1 = relu(dinv*agg1 + b1); g2 = dinv .* (h1 @ W2) ----------------
__global__ __launch_bounds__(256) void k_layer2(const float* __restrict__ agg1,
                                                const float* __restrict__ dinv,
                                                const float* __restrict__ b1,
                                                const float* __restrict__ W2,
                                                float* __restrict__ g2) {
    __shared__ float hs[32][65];   // +1 pad
    __shared__ float Ws[64 * 32];  // 8 KB
    for (int i = threadIdx.x; i < 64 * 32; i += 256) Ws[i] = W2[i];
    int row0 = blockIdx.x * 32;
    for (int i = threadIdx.x; i < 32 * 64; i += 256) {
        int r = i >> 6, f = i & 63;
        int row = row0 + r;
        float v = dinv[row] * agg1[(size_t)row * 64 + f] + b1[f];
        hs[r][f] = fmaxf(v, 0.f);
    }
    __syncthreads();
    int r = threadIdx.x >> 3;
    int j0 = (threadIdx.x & 7) * 4;
    int row = row0 + r;
    float a0 = 0.f, a1 = 0.f, a2 = 0.f, a3 = 0.f;
#pragma unroll 8
    for (int f = 0; f < 64; f++) {
        float h = hs[r][f];
        a0 += h * Ws[f * 32 + j0 + 0];
        a1 += h * Ws[f * 32 + j0 + 1];
        a2 += h * Ws[f * 32 + j0 + 2];
        a3 += h * Ws[f * 32 + j0 + 3];
    }
    float s = dinv[row];
    *reinterpret_cast<float4*>(&g2[(size_t)row * 32 + j0]) =
        make_float4(s * a0, s * a1, s * a2, s * a3);
}

// ---------------- layer 3: h2 = relu(dinv*agg2 + b2); g3 = dinv .* (h2 @ W3) ----------------
__global__ __launch_bounds__(256) void k_layer3(const float* __restrict__ agg2,
                                                const float* __restrict__ dinv,
                                                const float* __restrict__ b2,
                                                const float* __restrict__ W3,
                                                float* __restrict__ g3) {
    int row = blockIdx.x * blockDim.x + threadIdx.x;
    if (row >= N_NODES) return;
    float s = dinv[row];
    float t0 = 0.f, t1 = 0.f;
    const float4* ar = reinterpret_cast<const float4*>(agg2 + (size_t)row * 32);
#pragma unroll
    for (int q = 0; q < 8; q++) {
        float4 v = ar[q];
        float h;
        int f = q * 4;
        h = fmaxf(s * v.x + b2[f + 0], 0.f); t0 += h * W3[(f + 0) * 2]; t1 += h * W3[(f + 0) * 2 + 1];
        h = fmaxf(s * v.y + b2[f + 1], 0.f); t0 += h * W3[(f + 1) * 2]; t1 += h * W3[(f + 1) * 2 + 1];
        h = fmaxf(s * v.z + b2[f + 2], 0.f); t0 += h * W3[(f + 2) * 2]; t1 += h * W3[(f + 2) * 2 + 1];
        h = fmaxf(s * v.w + b2[f + 3], 0.f); t0 += h * W3[(f + 3) * 2]; t1 += h * W3[(f + 3) * 2 + 1];
    }
    g3[(size_t)row * 2 + 0] = s * t0;
    g3[(size_t)row * 2 + 1] = s * t1;
}

// ---------------- final: out = log_softmax(dinv*agg3 + b3) ----------------
__global__ void k_final(const float* __restrict__ agg3,
                        const float* __restrict__ dinv,
                        const float* __restrict__ b3,
                        float* __restrict__ out) {
    int row = blockIdx.x * blockDim.x + threadIdx.x;
    if (row >= N_NODES) return;
    float s = dinv[row];
    float z0 = s * agg3[(size_t)row * 2 + 0] + b3[0];
    float z1 = s * agg3[(size_t)row * 2 + 1] + b3[1];
    float m = fmaxf(z0, z1);
    float lse = m + logf(expf(z0 - m) + expf(z1 - m));
    out[(size_t)row * 2 + 0] = z0 - lse;
    out[(size_t)row * 2 + 1] = z1 - lse;
}

extern "C" void kernel_launch(void* const* d_in, const int* in_sizes, int n_in,
                              void* d_out, int out_size, void* d_ws, size_t ws_size,
                              hipStream_t stream) {
    const float* x  = (const float*)d_in[0];
    const int*   ei = (const int*)d_in[1];
    const float* W1 = (const float*)d_in[2];
    const float* b1 = (const float*)d_in[3];
    const float* W2 = (const float*)d_in[4];
    const float* b2 = (const float*)d_in[5];
    const float* W3 = (const float*)d_in[6];
    const float* b3 = (const float*)d_in[7];
    float* out = (float*)d_out;

    const int* src = ei;
    const int* dst = ei + N_EDGES;

    // ---- workspace layout (ints first, then floats; buffers aliased across layers) ----
    int* deg_i  = (int*)d_ws;                  // N   (also cur is next N -> zeroed together)
    int* cur    = deg_i + N_NODES;             // N
    int* bsums  = cur + N_NODES;               // 512
    int* boffs  = bsums + 512;                 // 512
    int* rowptr = boffs + 512;                 // N+1
    int* csr    = rowptr + (N_NODES + 1);      // E
    float* dinv = (float*)(csr + N_EDGES);     // N
    float* bufA = dinv + N_NODES;              // 64N  (g1, later g2, g3)
    float* bufB = bufA + (size_t)N_NODES * 64; // 64N  (agg1, later agg2, agg3)

    float* g1   = bufA;
    float* agg1 = bufB;
    float* g2   = bufA;   // g1 dead after gather64
    float* agg2 = bufB;   // agg1 dead after layer2
    float* g3   = bufA;
    float* agg3 = bufB;

    const int TB = 256;
    int nb_nodes = (N_NODES + TB - 1) / TB;       // 391
    int nb_edges = (N_EDGES + TB - 1) / TB;       // 12500

    k_zero<<<(2 * N_NODES + TB - 1) / TB, TB, 0, stream>>>(deg_i, 2 * N_NODES);
    k_count<<<nb_edges, TB, 0, stream>>>(dst, deg_i);
    k_dinv<<<nb_nodes, TB, 0, stream>>>(deg_i, dinv);
    k_scan1<<<NB_SCAN, 256, 0, stream>>>(deg_i, rowptr, bsums);
    k_scan2<<<1, 512, 0, stream>>>(bsums, boffs);
    k_scan3<<<NB_SCAN, 256, 0, stream>>>(rowptr, deg_i, boffs);
    k_fill<<<nb_edges, TB, 0, stream>>>(src, dst, rowptr, cur, csr);

    k_gemm1<<<N_NODES / 8, TB, 0, stream>>>(x, W1, dinv, g1);
    k_gather64<<<N_NODES / 4, TB, 0, stream>>>(rowptr, csr, g1, agg1);

    k_layer2<<<N_NODES / 32, TB, 0, stream>>>(agg1, dinv, b1, W2, g2);
    k_gather32<<<N_NODES / 8, TB, 0, stream>>>(rowptr, csr, g2, agg2);

    k_layer3<<<nb_nodes, TB, 0, stream>>>(agg2, dinv, b2, W3, g3);
    k_gather2<<<(2 * N_NODES + TB - 1) / TB, TB, 0, stream>>>(rowptr, csr, g3, agg3);

    k_final<<<nb_nodes, TB, 0, stream>>>(agg3, dinv, b3, out);
}

// Round 3
// 979.250 us; speedup vs baseline: 1.8806x; 1.1183x over previous
//
#include <hip/hip_runtime.h>
#include <hip/hip_bf16.h>
#include <math.h>

#define N_NODES 100000
#define N_EDGES 3200000
#define F0 489
#define KPAD 512
#define NB_SCAN 391   // ceil(100000/256)

typedef __attribute__((ext_vector_type(8))) short short8;
typedef __attribute__((ext_vector_type(4))) float f32x4;

__device__ __forceinline__ short f2bf(float v) {
    return __builtin_bit_cast(short, __float2bfloat16(v));
}

// ---------------- zero int buffer ----------------
__global__ void k_zero(int* a, int n) {
    int i = blockIdx.x * blockDim.x + threadIdx.x;
    if (i < n) a[i] = 0;
}

// ---------------- integer degree histogram (dst) ----------------
__global__ void k_count(const int* __restrict__ dst, int* deg) {
    int e = blockIdx.x * blockDim.x + threadIdx.x;
    if (e < N_EDGES) atomicAdd(&deg[dst[e]], 1);
}

// ---------------- dinv = rsqrt(deg+1)  (self loop) ----------------
__global__ void k_dinv(const int* __restrict__ deg, float* dinv) {
    int i = blockIdx.x * blockDim.x + threadIdx.x;
    if (i < N_NODES) dinv[i] = rsqrtf((float)deg[i] + 1.0f);
}

// ---------------- scan ----------------
__global__ __launch_bounds__(256) void k_scan1(const int* __restrict__ deg,
                                               int* __restrict__ rowptr,
                                               int* __restrict__ bsums) {
    __shared__ int tmp[256];
    int i = blockIdx.x * 256 + threadIdx.x;
    int v = (i < N_NODES) ? deg[i] : 0;
    tmp[threadIdx.x] = v;
    __syncthreads();
    for (int off = 1; off < 256; off <<= 1) {
        int t = (threadIdx.x >= off) ? tmp[threadIdx.x - off] : 0;
        __syncthreads();
        tmp[threadIdx.x] += t;
        __syncthreads();
    }
    if (i < N_NODES) rowptr[i] = tmp[threadIdx.x];
    if (threadIdx.x == 255) bsums[blockIdx.x] = tmp[255];
}

__global__ __launch_bounds__(512) void k_scan2(const int* __restrict__ bsums,
                                               int* __restrict__ boffs) {
    __shared__ int tmp[512];
    int i = threadIdx.x;
    int v = (i < NB_SCAN) ? bsums[i] : 0;
    tmp[i] = v;
    __syncthreads();
    for (int off = 1; off < 512; off <<= 1) {
        int t = (i >= off) ? tmp[i - off] : 0;
        __syncthreads();
        tmp[i] += t;
        __syncthreads();
    }
    if (i < NB_SCAN) boffs[i] = tmp[i] - v;
}

__global__ __launch_bounds__(256) void k_scan3(int* __restrict__ rowptr,
                                               const int* __restrict__ deg,
                                               const int* __restrict__ boffs) {
    int i = blockIdx.x * 256 + threadIdx.x;
    if (i < N_NODES) rowptr[i] = rowptr[i] - deg[i] + boffs[blockIdx.x];
    if (i == 0) rowptr[N_NODES] = N_EDGES;
}

// ---------------- CSR bucket fill ----------------
__global__ void k_fill(const int* __restrict__ src, const int* __restrict__ dst,
                       const int* __restrict__ rowptr, int* __restrict__ cur,
                       int* __restrict__ csr) {
    int e = blockIdx.x * blockDim.x + threadIdx.x;
    if (e < N_EDGES) {
        int d = dst[e];
        int pos = rowptr[d] + atomicAdd(&cur[d], 1);
        csr[pos] = src[e];
    }
}

// ---------------- W1 -> bf16, transposed+padded: Wt[n][k], n<64, k<512 ----------------
__global__ void k_cvtW(const float* __restrict__ W1, short* __restrict__ Wt) {
    int i = blockIdx.x * 256 + threadIdx.x;
    if (i < 64 * KPAD) {
        int n = i >> 9, k = i & (KPAD - 1);
        float v = (k < F0) ? W1[k * 64 + n] : 0.f;
        Wt[i] = f2bf(v);
    }
}

// ---------------- layer 1 MFMA GEMM: g1 = dinv .* (x @ W1) ----------------
// block = 256 (4 waves); each wave: 16 rows x 64 cols; grid = ceil(N/64).
__global__ __launch_bounds__(256) void k_gemm1_mfma(const float* __restrict__ x,
                                                    const short* __restrict__ Wt,
                                                    const float* __restrict__ dinv,
                                                    float* __restrict__ g1) {
    int wave = threadIdx.x >> 6;
    int lane = threadIdx.x & 63;
    int quad = lane >> 4;
    int m = lane & 15;
    int row0 = blockIdx.x * 64 + wave * 16;        // wave's first row
    int row = row0 + m;
    int rowc = row < N_NODES ? row : N_NODES - 1;  // clamp for loads
    const float* xr = x + (size_t)rowc * F0;

    f32x4 acc0 = {0.f, 0.f, 0.f, 0.f};
    f32x4 acc1 = {0.f, 0.f, 0.f, 0.f};
    f32x4 acc2 = {0.f, 0.f, 0.f, 0.f};
    f32x4 acc3 = {0.f, 0.f, 0.f, 0.f};

    const short* wb = Wt + m * KPAD + quad * 8;    // + tile*16*KPAD + ks*32

    for (int ks = 0; ks < 16; ks++) {
        int kb = ks * 32 + quad * 8;
        short8 af;
        if (kb + 8 <= F0) {
#pragma unroll
            for (int j = 0; j < 8; j++) af[j] = f2bf(xr[kb + j]);
        } else {
#pragma unroll
            for (int j = 0; j < 8; j++) af[j] = (kb + j < F0) ? f2bf(xr[kb + j]) : (short)0;
        }
        const short* wk = wb + ks * 32;
        short8 b0 = *(const short8*)(wk);
        short8 b1 = *(const short8*)(wk + 16 * KPAD);
        short8 b2 = *(const short8*)(wk + 32 * KPAD);
        short8 b3 = *(const short8*)(wk + 48 * KPAD);
        acc0 = __builtin_amdgcn_mfma_f32_16x16x32_bf16(af, b0, acc0, 0, 0, 0);
        acc1 = __builtin_amdgcn_mfma_f32_16x16x32_bf16(af, b1, acc1, 0, 0, 0);
        acc2 = __builtin_amdgcn_mfma_f32_16x16x32_bf16(af, b2, acc2, 0, 0, 0);
        acc3 = __builtin_amdgcn_mfma_f32_16x16x32_bf16(af, b3, acc3, 0, 0, 0);
    }

    // D layout: col = lane&15, row = quad*4 + reg
#pragma unroll
    for (int r = 0; r < 4; r++) {
        int orow = row0 + quad * 4 + r;
        if (orow < N_NODES) {
            float s = dinv[orow];
            float* gr = g1 + (size_t)orow * 64 + m;
            gr[0]  = s * acc0[r];
            gr[16] = s * acc1[r];
            gr[32] = s * acc2[r];
            gr[48] = s * acc3[r];
        }
    }
}

// ---------------- gather, 64 features ----------------
__global__ __launch_bounds__(256) void k_gather64(const int* __restrict__ rowptr,
                                                  const int* __restrict__ csr,
                                                  const float* __restrict__ g,
                                                  float* __restrict__ agg) {
    int node = blockIdx.x * 4 + (threadIdx.x >> 6);
    int f = threadIdx.x & 63;
    int beg = rowptr[node], end = rowptr[node + 1];
    float acc = g[(size_t)node * 64 + f];  // self loop
    for (int j0 = beg; j0 < end; j0 += 64) {
        int n = end - j0;
        if (n > 64) n = 64;
        int e = csr[j0 + (f < n ? f : 0)];
        for (int i = 0; i < n; i++) {
            int s = __shfl(e, i, 64);
            acc += g[(size_t)s * 64 + f];
        }
    }
    agg[(size_t)node * 64 + f] = acc;
}

// ---------------- gather, 32 features ----------------
__global__ __launch_bounds__(256) void k_gather32(const int* __restrict__ rowptr,
                                                  const int* __restrict__ csr,
                                                  const float* __restrict__ g,
                                                  float* __restrict__ agg) {
    int t = blockIdx.x * 256 + threadIdx.x;
    int node = t >> 5;
    int f = t & 31;
    int beg = rowptr[node], end = rowptr[node + 1];
    float acc = g[(size_t)node * 32 + f];
    for (int j0 = beg; j0 < end; j0 += 32) {
        int n = end - j0;
        if (n > 32) n = 32;
        int e = csr[j0 + (f < n ? f : 0)];
        for (int i = 0; i < n; i++) {
            int s = __shfl(e, i, 32);
            acc += g[(size_t)s * 32 + f];
        }
    }
    agg[(size_t)node * 32 + f] = acc;
}

// ---------------- gather, 2 features ----------------
__global__ __launch_bounds__(256) void k_gather2(const int* __restrict__ rowptr,
                                                 const int* __restrict__ csr,
                                                 const float* __restrict__ g,
                                                 float* __restrict__ agg) {
    int t = blockIdx.x * 256 + threadIdx.x;
    if (t >= N_NODES * 2) return;
    int node = t >> 1;
    int f = t & 1;
    int beg = rowptr[node], end = rowptr[node + 1];
    float acc = g[(size_t)node * 2 + f];
    for (int j = beg; j < end; j++) {
        int s = csr[j];
        acc += g[(size_t)s * 2 + f];
    }
    agg[(size_t)node * 2 + f] = acc;
}

// ---------------- layer 2 ----------------
__global__ __launch_bounds__(256) void k_layer2(const float* __restrict__ agg1,
                                                const float* __restrict__ dinv,
                                                const float* __restrict__ b1,
                                                const float* __restrict__ W2,
                                                float* __restrict__ g2) {
    __shared__ float hs[32][65];
    __shared__ float Ws[64 * 32];
    for (int i = threadIdx.x; i < 64 * 32; i += 256) Ws[i] = W2[i];
    int row0 = blockIdx.x * 32;
    for (int i = threadIdx.x; i < 32 * 64; i += 256) {
        int r = i >> 6, f = i & 63;
        int row = row0 + r;
        float v = dinv[row] * agg1[(size_t)row * 64 + f] + b1[f];
        hs[r][f] = fmaxf(v, 0.f);
    }
    __syncthreads();
    int r = threadIdx.x >> 3;
    int j0 = (threadIdx.x & 7) * 4;
    int row = row0 + r;
    float a0 = 0.f, a1 = 0.f, a2 = 0.f, a3 = 0.f;
#pragma unroll 8
    for (int f = 0; f < 64; f++) {
        float h = hs[r][f];
        a0 += h * Ws[f * 32 + j0 + 0];
        a1 += h * Ws[f * 32 + j0 + 1];
        a2 += h * Ws[f * 32 + j0 + 2];
        a3 += h * Ws[f * 32 + j0 + 3];
    }
    float s = dinv[row];
    *reinterpret_cast<float4*>(&g2[(size_t)row * 32 + j0]) =
        make_float4(s * a0, s * a1, s * a2, s * a3);
}

// ---------------- layer 3 ----------------
__global__ __launch_bounds__(256) void k_layer3(const float* __restrict__ agg2,
                                                const float* __restrict__ dinv,
                                                const float* __restrict__ b2,
                                                const float* __restrict__ W3,
                                                float* __restrict__ g3) {
    int row = blockIdx.x * blockDim.x + threadIdx.x;
    if (row >= N_NODES) return;
    float s = dinv[row];
    float t0 = 0.f, t1 = 0.f;
    const float4* ar = reinterpret_cast<const float4*>(agg2 + (size_t)row * 32);
#pragma unroll
    for (int q = 0; q < 8; q++) {
        float4 v = ar[q];
        float h;
        int f = q * 4;
        h = fmaxf(s * v.x + b2[f + 0], 0.f); t0 += h * W3[(f + 0) * 2]; t1 += h * W3[(f + 0) * 2 + 1];
        h = fmaxf(s * v.y + b2[f + 1], 0.f); t0 += h * W3[(f + 1) * 2]; t1 += h * W3[(f + 1) * 2 + 1];
        h = fmaxf(s * v.z + b2[f + 2], 0.f); t0 += h * W3[(f + 2) * 2]; t1 += h * W3[(f + 2) * 2 + 1];
        h = fmaxf(s * v.w + b2[f + 3], 0.f); t0 += h * W3[(f + 3) * 2]; t1 += h * W3[(f + 3) * 2 + 1];
    }
    g3[(size_t)row * 2 + 0] = s * t0;
    g3[(size_t)row * 2 + 1] = s * t1;
}

// ---------------- final log_softmax ----------------
__global__ void k_final(const float* __restrict__ agg3,
                        const float* __restrict__ dinv,
                        const float* __restrict__ b3,
                        float* __restrict__ out) {
    int row = blockIdx.x * blockDim.x + threadIdx.x;
    if (row >= N_NODES) return;
    float s = dinv[row];
    float z0 = s * agg3[(size_t)row * 2 + 0] + b3[0];
    float z1 = s * agg3[(size_t)row * 2 + 1] + b3[1];
    float m = fmaxf(z0, z1);
    float lse = m + logf(expf(z0 - m) + expf(z1 - m));
    out[(size_t)row * 2 + 0] = z0 - lse;
    out[(size_t)row * 2 + 1] = z1 - lse;
}

extern "C" void kernel_launch(void* const* d_in, const int* in_sizes, int n_in,
                              void* d_out, int out_size, void* d_ws, size_t ws_size,
                              hipStream_t stream) {
    const float* x  = (const float*)d_in[0];
    const int*   ei = (const int*)d_in[1];
    const float* W1 = (const float*)d_in[2];
    const float* b1 = (const float*)d_in[3];
    const float* W2 = (const float*)d_in[4];
    const float* b2 = (const float*)d_in[5];
    const float* W3 = (const float*)d_in[6];
    const float* b3 = (const float*)d_in[7];
    float* out = (float*)d_out;

    const int* src = ei;
    const int* dst = ei + N_EDGES;

    // ---- workspace layout (element offsets in 4-byte units; 16B-aligned blocks) ----
    int* deg_i  = (int*)d_ws;                    // 100000
    int* cur    = deg_i + 100000;                // 100000
    int* bsums  = cur + 100000;                  // 512
    int* boffs  = bsums + 512;                   // 512
    int* rowptr = boffs + 512;                   // 100001 (pad to 100004)
    int* csr    = rowptr + 100004;               // 3200000
    float* dinv = (float*)(csr + 3200000);       // 100000
    short* Wt   = (short*)(dinv + 100000);       // 64*512 bf16 = 16384 ints
    float* bufA = (float*)((int*)Wt + 16384);    // 6.4M
    float* bufB = bufA + (size_t)N_NODES * 64;   // 6.4M

    float* g1   = bufA;
    float* agg1 = bufB;
    float* g2   = bufA;
    float* agg2 = bufB;
    float* g3   = bufA;
    float* agg3 = bufB;

    const int TB = 256;
    int nb_nodes = (N_NODES + TB - 1) / TB;       // 391
    int nb_edges = (N_EDGES + TB - 1) / TB;       // 12500

    k_zero<<<(2 * N_NODES + TB - 1) / TB, TB, 0, stream>>>(deg_i, 2 * N_NODES);
    k_count<<<nb_edges, TB, 0, stream>>>(dst, deg_i);
    k_dinv<<<nb_nodes, TB, 0, stream>>>(deg_i, dinv);
    k_scan1<<<NB_SCAN, 256, 0, stream>>>(deg_i, rowptr, bsums);
    k_scan2<<<1, 512, 0, stream>>>(bsums, boffs);
    k_scan3<<<NB_SCAN, 256, 0, stream>>>(rowptr, deg_i, boffs);
    k_fill<<<nb_edges, TB, 0, stream>>>(src, dst, rowptr, cur, csr);
    k_cvtW<<<(64 * KPAD + 255) / 256, 256, 0, stream>>>(W1, Wt);

    k_gemm1_mfma<<<(N_NODES + 63) / 64, TB, 0, stream>>>(x, Wt, dinv, g1);
    k_gather64<<<N_NODES / 4, TB, 0, stream>>>(rowptr, csr, g1, agg1);

    k_layer2<<<N_NODES / 32, TB, 0, stream>>>(agg1, dinv, b1, W2, g2);
    k_gather32<<<N_NODES / 8, TB, 0, stream>>>(rowptr, csr, g2, agg2);

    k_layer3<<<nb_nodes, TB, 0, stream>>>(agg2, dinv, b2, W3, g3);
    k_gather2<<<(2 * N_NODES + TB - 1) / TB, TB, 0, stream>>>(rowptr, csr, g3, agg3);

    k_final<<<nb_nodes, TB, 0, stream>>>(agg3, dinv, b3, out);
}

// Round 4
// 851.573 us; speedup vs baseline: 2.1626x; 1.1499x over previous
//
#include <hip/hip_runtime.h>
#include <hip/hip_bf16.h>
#include <math.h>

#define N_NODES 100000
#define N_EDGES 3200000
#define F0 489
#define KPAD 512
#define NB_SCAN 391   // ceil(100000/256)

typedef __attribute__((ext_vector_type(8))) short short8;
typedef __attribute__((ext_vector_type(4))) float f32x4;
typedef unsigned short ushort_t;
typedef unsigned int uint_t;

__device__ __forceinline__ short f2bf(float v) {
    return __builtin_bit_cast(short, __float2bfloat16(v));
}
__device__ __forceinline__ float bf2f(ushort_t u) {
    union { uint_t i; float f; } c;
    c.i = ((uint_t)u) << 16;
    return c.f;
}

// ---------------- zero int buffer ----------------
__global__ void k_zero(int* a, int n) {
    int i = blockIdx.x * blockDim.x + threadIdx.x;
    if (i < n) a[i] = 0;
}

// ---------------- integer degree histogram (dst) ----------------
__global__ void k_count(const int* __restrict__ dst, int* deg) {
    int e = blockIdx.x * blockDim.x + threadIdx.x;
    if (e < N_EDGES) atomicAdd(&deg[dst[e]], 1);
}

// ---------------- scan ----------------
__global__ __launch_bounds__(256) void k_scan1(const int* __restrict__ deg,
                                               int* __restrict__ rowptr,
                                               int* __restrict__ bsums) {
    __shared__ int tmp[256];
    int i = blockIdx.x * 256 + threadIdx.x;
    int v = (i < N_NODES) ? deg[i] : 0;
    tmp[threadIdx.x] = v;
    __syncthreads();
    for (int off = 1; off < 256; off <<= 1) {
        int t = (threadIdx.x >= off) ? tmp[threadIdx.x - off] : 0;
        __syncthreads();
        tmp[threadIdx.x] += t;
        __syncthreads();
    }
    if (i < N_NODES) rowptr[i] = tmp[threadIdx.x];
    if (threadIdx.x == 255) bsums[blockIdx.x] = tmp[255];
}

__global__ __launch_bounds__(512) void k_scan2(const int* __restrict__ bsums,
                                               int* __restrict__ boffs) {
    __shared__ int tmp[512];
    int i = threadIdx.x;
    int v = (i < NB_SCAN) ? bsums[i] : 0;
    tmp[i] = v;
    __syncthreads();
    for (int off = 1; off < 512; off <<= 1) {
        int t = (i >= off) ? tmp[i - off] : 0;
        __syncthreads();
        tmp[i] += t;
        __syncthreads();
    }
    if (i < NB_SCAN) boffs[i] = tmp[i] - v;
}

// also computes dinv = rsqrt(deg+1)
__global__ __launch_bounds__(256) void k_scan3(int* __restrict__ rowptr,
                                               const int* __restrict__ deg,
                                               const int* __restrict__ boffs,
                                               float* __restrict__ dinv) {
    int i = blockIdx.x * 256 + threadIdx.x;
    if (i < N_NODES) {
        int d = deg[i];
        rowptr[i] = rowptr[i] - d + boffs[blockIdx.x];
        dinv[i] = rsqrtf((float)d + 1.0f);
    }
    if (i == 0) rowptr[N_NODES] = N_EDGES;
}

// ---------------- CSR bucket fill ----------------
__global__ void k_fill(const int* __restrict__ src, const int* __restrict__ dst,
                       const int* __restrict__ rowptr, int* __restrict__ cur,
                       int* __restrict__ csr) {
    int e = blockIdx.x * blockDim.x + threadIdx.x;
    if (e < N_EDGES) {
        int d = dst[e];
        int pos = rowptr[d] + atomicAdd(&cur[d], 1);
        csr[pos] = src[e];
    }
}

// ---------------- W1 -> bf16, transposed+padded: Wt[n][k], n<64, k<512 ----------------
__global__ void k_cvtW(const float* __restrict__ W1, short* __restrict__ Wt) {
    int i = blockIdx.x * 256 + threadIdx.x;
    if (i < 64 * KPAD) {
        int n = i >> 9, k = i & (KPAD - 1);
        float v = (k < F0) ? W1[k * 64 + n] : 0.f;
        Wt[i] = f2bf(v);
    }
}

// ---------------- layer 1 MFMA GEMM: g1 = bf16( dinv .* (x @ W1) ) ----------------
__global__ __launch_bounds__(256) void k_gemm1_mfma(const float* __restrict__ x,
                                                    const short* __restrict__ Wt,
                                                    const float* __restrict__ dinv,
                                                    ushort_t* __restrict__ g1) {
    int wave = threadIdx.x >> 6;
    int lane = threadIdx.x & 63;
    int quad = lane >> 4;
    int m = lane & 15;
    int row0 = blockIdx.x * 64 + wave * 16;
    int row = row0 + m;
    int rowc = row < N_NODES ? row : N_NODES - 1;
    const float* xr = x + (size_t)rowc * F0;

    f32x4 acc0 = {0.f, 0.f, 0.f, 0.f};
    f32x4 acc1 = {0.f, 0.f, 0.f, 0.f};
    f32x4 acc2 = {0.f, 0.f, 0.f, 0.f};
    f32x4 acc3 = {0.f, 0.f, 0.f, 0.f};

    const short* wb = Wt + m * KPAD + quad * 8;

    for (int ks = 0; ks < 16; ks++) {
        int kb = ks * 32 + quad * 8;
        short8 af;
        if (kb + 8 <= F0) {
#pragma unroll
            for (int j = 0; j < 8; j++) af[j] = f2bf(xr[kb + j]);
        } else {
#pragma unroll
            for (int j = 0; j < 8; j++) af[j] = (kb + j < F0) ? f2bf(xr[kb + j]) : (short)0;
        }
        const short* wk = wb + ks * 32;
        short8 b0 = *(const short8*)(wk);
        short8 b1 = *(const short8*)(wk + 16 * KPAD);
        short8 b2 = *(const short8*)(wk + 32 * KPAD);
        short8 b3 = *(const short8*)(wk + 48 * KPAD);
        acc0 = __builtin_amdgcn_mfma_f32_16x16x32_bf16(af, b0, acc0, 0, 0, 0);
        acc1 = __builtin_amdgcn_mfma_f32_16x16x32_bf16(af, b1, acc1, 0, 0, 0);
        acc2 = __builtin_amdgcn_mfma_f32_16x16x32_bf16(af, b2, acc2, 0, 0, 0);
        acc3 = __builtin_amdgcn_mfma_f32_16x16x32_bf16(af, b3, acc3, 0, 0, 0);
    }

    // D layout: col = lane&15, row = quad*4 + reg
#pragma unroll
    for (int r = 0; r < 4; r++) {
        int orow = row0 + quad * 4 + r;
        if (orow < N_NODES) {
            float s = dinv[orow];
            ushort_t* gr = g1 + (size_t)orow * 64 + m;
            gr[0]  = (ushort_t)f2bf(s * acc0[r]);
            gr[16] = (ushort_t)f2bf(s * acc1[r]);
            gr[32] = (ushort_t)f2bf(s * acc2[r]);
            gr[48] = (ushort_t)f2bf(s * acc3[r]);
        }
    }
}

// ---------------- gather, 64 bf16 features -> fp32 agg ----------------
__global__ __launch_bounds__(256) void k_gather64(const int* __restrict__ rowptr,
                                                  const int* __restrict__ csr,
                                                  const ushort_t* __restrict__ g,
                                                  float* __restrict__ agg) {
    int node = blockIdx.x * 4 + (threadIdx.x >> 6);
    int f = threadIdx.x & 63;
    int beg = rowptr[node], end = rowptr[node + 1];
    float acc = bf2f(g[(size_t)node * 64 + f]);  // self loop
    for (int j0 = beg; j0 < end; j0 += 64) {
        int n = end - j0;
        if (n > 64) n = 64;
        int e = csr[j0 + (f < n ? f : 0)];
        float a0 = 0.f, a1 = 0.f;
        int i = 0;
        for (; i + 2 <= n; i += 2) {
            int s0 = __shfl(e, i, 64);
            int s1 = __shfl(e, i + 1, 64);
            a0 += bf2f(g[(size_t)s0 * 64 + f]);
            a1 += bf2f(g[(size_t)s1 * 64 + f]);
        }
        if (i < n) {
            int s0 = __shfl(e, i, 64);
            a0 += bf2f(g[(size_t)s0 * 64 + f]);
        }
        acc += a0 + a1;
    }
    agg[(size_t)node * 64 + f] = acc;
}

// ---------------- gather, 32 bf16 features -> fp32 agg ----------------
__global__ __launch_bounds__(256) void k_gather32(const int* __restrict__ rowptr,
                                                  const int* __restrict__ csr,
                                                  const ushort_t* __restrict__ g,
                                                  float* __restrict__ agg) {
    int t = blockIdx.x * 256 + threadIdx.x;
    int node = t >> 5;
    int f = t & 31;
    int beg = rowptr[node], end = rowptr[node + 1];
    float acc = bf2f(g[(size_t)node * 32 + f]);
    for (int j0 = beg; j0 < end; j0 += 32) {
        int n = end - j0;
        if (n > 32) n = 32;
        int e = csr[j0 + (f < n ? f : 0)];
        float a0 = 0.f, a1 = 0.f;
        int i = 0;
        for (; i + 2 <= n; i += 2) {
            int s0 = __shfl(e, i, 32);
            int s1 = __shfl(e, i + 1, 32);
            a0 += bf2f(g[(size_t)s0 * 32 + f]);
            a1 += bf2f(g[(size_t)s1 * 32 + f]);
        }
        if (i < n) {
            int s0 = __shfl(e, i, 32);
            a0 += bf2f(g[(size_t)s0 * 32 + f]);
        }
        acc += a0 + a1;
    }
    agg[(size_t)node * 32 + f] = acc;
}

// ---------------- gather, 2 fp32 features ----------------
__global__ __launch_bounds__(256) void k_gather2(const int* __restrict__ rowptr,
                                                 const int* __restrict__ csr,
                                                 const float* __restrict__ g,
                                                 float* __restrict__ agg) {
    int t = blockIdx.x * 256 + threadIdx.x;
    if (t >= N_NODES * 2) return;
    int node = t >> 1;
    int f = t & 1;
    int beg = rowptr[node], end = rowptr[node + 1];
    float acc = g[(size_t)node * 2 + f];
    for (int j = beg; j < end; j++) {
        int s = csr[j];
        acc += g[(size_t)s * 2 + f];
    }
    agg[(size_t)node * 2 + f] = acc;
}

// ---------------- layer 2: g2 = bf16( dinv .* (relu(dinv*agg1+b1) @ W2) ) ----------------
__global__ __launch_bounds__(256) void k_layer2(const float* __restrict__ agg1,
                                                const float* __restrict__ dinv,
                                                const float* __restrict__ b1,
                                                const float* __restrict__ W2,
                                                ushort_t* __restrict__ g2) {
    __shared__ float hs[32][65];
    __shared__ float Ws[64 * 32];
    for (int i = threadIdx.x; i < 64 * 32; i += 256) Ws[i] = W2[i];
    int row0 = blockIdx.x * 32;
    for (int i = threadIdx.x; i < 32 * 64; i += 256) {
        int r = i >> 6, f = i & 63;
        int row = row0 + r;
        float v = dinv[row] * agg1[(size_t)row * 64 + f] + b1[f];
        hs[r][f] = fmaxf(v, 0.f);
    }
    __syncthreads();
    int r = threadIdx.x >> 3;
    int j0 = (threadIdx.x & 7) * 4;
    int row = row0 + r;
    float a0 = 0.f, a1 = 0.f, a2 = 0.f, a3 = 0.f;
#pragma unroll 8
    for (int f = 0; f < 64; f++) {
        float h = hs[r][f];
        a0 += h * Ws[f * 32 + j0 + 0];
        a1 += h * Ws[f * 32 + j0 + 1];
        a2 += h * Ws[f * 32 + j0 + 2];
        a3 += h * Ws[f * 32 + j0 + 3];
    }
    float s = dinv[row];
    ushort_t* gr = g2 + (size_t)row * 32 + j0;
    gr[0] = (ushort_t)f2bf(s * a0);
    gr[1] = (ushort_t)f2bf(s * a1);
    gr[2] = (ushort_t)f2bf(s * a2);
    gr[3] = (ushort_t)f2bf(s * a3);
}

// ---------------- layer 3 ----------------
__global__ __launch_bounds__(256) void k_layer3(const float* __restrict__ agg2,
                                                const float* __restrict__ dinv,
                                                const float* __restrict__ b2,
                                                const float* __restrict__ W3,
                                                float* __restrict__ g3) {
    int row = blockIdx.x * blockDim.x + threadIdx.x;
    if (row >= N_NODES) return;
    float s = dinv[row];
    float t0 = 0.f, t1 = 0.f;
    const float4* ar = reinterpret_cast<const float4*>(agg2 + (size_t)row * 32);
#pragma unroll
    for (int q = 0; q < 8; q++) {
        float4 v = ar[q];
        float h;
        int f = q * 4;
        h = fmaxf(s * v.x + b2[f + 0], 0.f); t0 += h * W3[(f + 0) * 2]; t1 += h * W3[(f + 0) * 2 + 1];
        h = fmaxf(s * v.y + b2[f + 1], 0.f); t0 += h * W3[(f + 1) * 2]; t1 += h * W3[(f + 1) * 2 + 1];
        h = fmaxf(s * v.z + b2[f + 2], 0.f); t0 += h * W3[(f + 2) * 2]; t1 += h * W3[(f + 2) * 2 + 1];
        h = fmaxf(s * v.w + b2[f + 3], 0.f); t0 += h * W3[(f + 3) * 2]; t1 += h * W3[(f + 3) * 2 + 1];
    }
    g3[(size_t)row * 2 + 0] = s * t0;
    g3[(size_t)row * 2 + 1] = s * t1;
}

// ---------------- final log_softmax ----------------
__global__ void k_final(const float* __restrict__ agg3,
                        const float* __restrict__ dinv,
                        const float* __restrict__ b3,
                        float* __restrict__ out) {
    int row = blockIdx.x * blockDim.x + threadIdx.x;
    if (row >= N_NODES) return;
    float s = dinv[row];
    float z0 = s * agg3[(size_t)row * 2 + 0] + b3[0];
    float z1 = s * agg3[(size_t)row * 2 + 1] + b3[1];
    float m = fmaxf(z0, z1);
    float lse = m + logf(expf(z0 - m) + expf(z1 - m));
    out[(size_t)row * 2 + 0] = z0 - lse;
    out[(size_t)row * 2 + 1] = z1 - lse;
}

extern "C" void kernel_launch(void* const* d_in, const int* in_sizes, int n_in,
                              void* d_out, int out_size, void* d_ws, size_t ws_size,
                              hipStream_t stream) {
    const float* x  = (const float*)d_in[0];
    const int*   ei = (const int*)d_in[1];
    const float* W1 = (const float*)d_in[2];
    const float* b1 = (const float*)d_in[3];
    const float* W2 = (const float*)d_in[4];
    const float* b2 = (const float*)d_in[5];
    const float* W3 = (const float*)d_in[6];
    const float* b3 = (const float*)d_in[7];
    float* out = (float*)d_out;

    const int* src = ei;
    const int* dst = ei + N_EDGES;

    // ---- workspace layout ----
    int* deg_i  = (int*)d_ws;                    // 100000
    int* cur    = deg_i + 100000;                // 100000
    int* bsums  = cur + 100000;                  // 512
    int* boffs  = bsums + 512;                   // 512
    int* rowptr = boffs + 512;                   // 100001 (pad 100004)
    int* csr    = rowptr + 100004;               // 3200000
    float* dinv = (float*)(csr + 3200000);       // 100000
    short* Wt   = (short*)(dinv + 100000);       // 32768 shorts = 16384 ints
    ushort_t* gbuf = (ushort_t*)((int*)Wt + 16384); // N*64 ushorts = 12.8 MB (gb1/gb2/g3)
    float* aggF = (float*)(gbuf + (size_t)N_NODES * 64); // N*64 fp32 = 25.6 MB

    ushort_t* gb1 = gbuf;
    ushort_t* gb2 = gbuf;                        // gb1 dead after gather64
    float* g3     = (float*)gbuf;                // gb2 dead after gather32 (N*2 fp32)
    float* agg1 = aggF;
    float* agg2 = aggF;                          // agg1 dead after layer2
    float* agg3 = aggF;                          // agg2 dead after layer3

    const int TB = 256;
    int nb_nodes = (N_NODES + TB - 1) / TB;      // 391
    int nb_edges = (N_EDGES + TB - 1) / TB;      // 12500

    k_zero<<<(2 * N_NODES + TB - 1) / TB, TB, 0, stream>>>(deg_i, 2 * N_NODES);
    k_count<<<nb_edges, TB, 0, stream>>>(dst, deg_i);
    k_scan1<<<NB_SCAN, 256, 0, stream>>>(deg_i, rowptr, bsums);
    k_scan2<<<1, 512, 0, stream>>>(bsums, boffs);
    k_scan3<<<NB_SCAN, 256, 0, stream>>>(rowptr, deg_i, boffs, dinv);
    k_fill<<<nb_edges, TB, 0, stream>>>(src, dst, rowptr, cur, csr);
    k_cvtW<<<(64 * KPAD + 255) / 256, 256, 0, stream>>>(W1, Wt);

    k_gemm1_mfma<<<(N_NODES + 63) / 64, TB, 0, stream>>>(x, Wt, dinv, gb1);
    k_gather64<<<N_NODES / 4, TB, 0, stream>>>(rowptr, csr, gb1, agg1);

    k_layer2<<<N_NODES / 32, TB, 0, stream>>>(agg1, dinv, b1, W2, gb2);
    k_gather32<<<N_NODES / 8, TB, 0, stream>>>(rowptr, csr, gb2, agg2);

    k_layer3<<<nb_nodes, TB, 0, stream>>>(agg2, dinv, b2, W3, g3);
    k_gather2<<<(2 * N_NODES + TB - 1) / TB, TB, 0, stream>>>(rowptr, csr, g3, agg3);

    k_final<<<nb_nodes, TB, 0, stream>>>(agg3, dinv, b3, out);
}